// Round 5
// baseline (165.453 us; speedup 1.0000x reference)
//
#include <hip/hip_runtime.h>
#include <stdint.h>

// Trilinear grid_sample of 256^3 fp32 volume, x100. Round 5: bucket pipeline,
// fixed. trilinear = wz0*bilerp(plane z0) + wz1*bilerp(plane z1); route the 2
// contributions per point into 512 (z, y-half) buckets; per-bucket block
// stages its 129-row half-plane COALESCED into LDS (bf16 x100, 67 KB -> 2
// blocks/CU) and serves bilerps from LDS, accumulating straight into out[]
// with float atomics (out pre-zeroed by async memset).
// R4 lesson: NO nontemporal hints on scattered stores (NT forced partial-line
// HBM write-through: 43 MB @ 1 TB/s, 45 us). Records now plain stores in
// 64 B runs (4 recs per block-bucket), absorbed by L2.

#define NBUCK 512           // 256 z-planes * 2 y-halves
#define OVCAP 65536
#define PROW 260            // plane row stride in u16 (8B-aligned rows)

typedef float v4f __attribute__((ext_vector_type(4)));

// ---------- shared routing math ------------------------------------------
struct Route {
  float ix, iy;
  int bA, bB;
  float wA, wB;
};

__device__ __forceinline__ Route make_route(const float* __restrict__ x, int i) {
  float gx = x[3 * i + 0] * 2.0f;
  float gy = x[3 * i + 1] * 2.0f;
  float gz = x[3 * i + 2] * 2.0f;
  Route r;
  r.ix = ((gx + 1.0f) * 256.0f - 1.0f) * 0.5f;   // in [-0.5, 255.5]
  r.iy = ((gy + 1.0f) * 256.0f - 1.0f) * 0.5f;
  float iz = ((gz + 1.0f) * 256.0f - 1.0f) * 0.5f;
  float z0f = floorf(iz);
  float tz = iz - z0f;
  int z0 = (int)z0f;                              // in [-1, 255]
  int zA = max(z0, 0);
  int zB = min(z0 + 1, 255);
  r.wA = (z0 >= 0) ? (1.0f - tz) : 0.0f;
  r.wB = (z0 + 1 <= 255) ? tz : 0.0f;
  int y0 = (int)floorf(r.iy);                     // in [-1, 255]
  int q = min(max(y0, 0), 255) >> 7;              // y-half containing rows y0,y0+1
  r.bA = zA * 2 + q;
  r.bB = zB * 2 + q;
  return r;
}

// bf16 round-to-nearest-even (values finite, never NaN)
__device__ __forceinline__ uint16_t bf16_rne(float f) {
  uint32_t u = __float_as_uint(f);
  u += 0x7FFFu + ((u >> 16) & 1u);
  return (uint16_t)(u >> 16);
}
__device__ __forceinline__ float b2f(uint16_t h) {
  return __uint_as_float(((uint32_t)h) << 16);
}

// ---------- kernel 1: fused LDS-hist + reservation + scatter --------------
__global__ __launch_bounds__(1024) void scatter_kernel(
    const float* __restrict__ x,
    uint32_t* __restrict__ cur,      // [NBUCK] fill counts (pre-zeroed)
    uint32_t* __restrict__ ovn,      // overflow count (pre-zeroed)
    uint32_t* __restrict__ ovbkt,    // [OVCAP]
    v4f* __restrict__ ovrec,         // [OVCAP]
    v4f* __restrict__ recs,          // [NBUCK * cap]
    int cap, int n)
{
  __shared__ uint32_t lh[NBUCK];
  __shared__ uint32_t gb[NBUCK];
  int t = threadIdx.x;
  if (t < NBUCK) lh[t] = 0;
  __syncthreads();

  int i = blockIdx.x * 1024 + t;
  bool act = (i < n);
  Route r;
  uint32_t lrA = 0, lrB = 0;
  if (act) {
    r = make_route(x, i);
    lrA = atomicAdd(&lh[r.bA], 1u);
    lrB = atomicAdd(&lh[r.bB], 1u);
  }
  __syncthreads();

  if (t < NBUCK) {
    uint32_t c = lh[t];
    gb[t] = c ? atomicAdd(&cur[t], c) : 0u;  // one global atomic per (block,bucket)
  }
  __syncthreads();

  if (act) {
    v4f ra = { r.ix, r.iy, r.wA, __uint_as_float((uint32_t)i) };
    v4f rb = { r.ix, r.iy, r.wB, __uint_as_float((uint32_t)i) };
    uint32_t pA = gb[r.bA] + lrA;
    if (pA < (uint32_t)cap) {
      recs[(size_t)r.bA * cap + pA] = ra;     // plain store: coalesce in L2
    } else {
      uint32_t o = atomicAdd(ovn, 1u);
      if (o < OVCAP) { ovbkt[o] = (uint32_t)r.bA; ovrec[o] = ra; }
    }
    uint32_t pB = gb[r.bB] + lrB;
    if (pB < (uint32_t)cap) {
      recs[(size_t)r.bB * cap + pB] = rb;
    } else {
      uint32_t o = atomicAdd(ovn, 1u);
      if (o < OVCAP) { ovbkt[o] = (uint32_t)r.bB; ovrec[o] = rb; }
    }
  }
}

// ---------- kernel 2: per-bucket LDS bilerp + atomic accumulate -----------
__device__ __forceinline__ void process_rec(
    v4f rec, const uint16_t* __restrict__ plane, int sq,
    float* __restrict__ out)
{
  float ixf = rec.x, iyf = rec.y, w = rec.z;
  uint32_t dest = __float_as_uint(rec.w);
  float x0f = floorf(ixf); float tx = ixf - x0f; int x0 = (int)x0f;
  float y0f = floorf(iyf); float ty = iyf - y0f; int y0 = (int)y0f;
  float wx0 = (x0 >= 0)   ? (1.0f - tx) : 0.0f;
  float wx1 = (x0 <= 254) ? tx : 0.0f;
  float wy0 = (y0 >= 0)   ? (1.0f - ty) : 0.0f;
  float wy1 = (y0 <= 254) ? ty : 0.0f;
  int xc0 = max(x0, 0), xc1 = min(x0 + 1, 255);
  int ly0 = max(y0, 0) - sq;          // in [0,128] by half construction
  int ly1 = min(y0 + 1, 255) - sq;    // in [0,128]
  float v00 = b2f(plane[ly0 * PROW + xc0]);
  float v01 = b2f(plane[ly0 * PROW + xc1]);
  float v10 = b2f(plane[ly1 * PROW + xc0]);
  float v11 = b2f(plane[ly1 * PROW + xc1]);
  float bil = (v00 * wx0 + v01 * wx1) * wy0 + (v10 * wx0 + v11 * wx1) * wy1;
  atomicAdd(&out[dest], w * bil);
}

__global__ __launch_bounds__(1024) void gather_kernel(
    const float* __restrict__ vol,
    const v4f* __restrict__ recs,
    const uint32_t* __restrict__ cur,
    const uint32_t* __restrict__ ovn,
    const uint32_t* __restrict__ ovbkt,
    const v4f* __restrict__ ovrec,
    float* __restrict__ out, int cap)
{
  int b = blockIdx.x;
  int z = b >> 1, q = b & 1;
  int sq = q << 7;                      // half row start: 0 or 128
  int nrows = q ? 128 : 129;            // q0 needs row 128 too (y0=127 case)
  __shared__ uint16_t plane[129 * PROW];  // 67,080 B -> 2 blocks/CU

  // coalesced staging: nrows x 256 floats as float4, convert bf16 x100
  const float* src = vol + ((size_t)(z * 256 + sq) * 256);
  for (int e = threadIdx.x; e < nrows * 64; e += 1024) {
    int rr = e >> 6, c4 = (e & 63) << 2;
    v4f v = *((const v4f*)(src + (size_t)rr * 256) + (e & 63));
    uint64_t p = (uint64_t)bf16_rne(100.0f * v.x)
               | ((uint64_t)bf16_rne(100.0f * v.y) << 16)
               | ((uint64_t)bf16_rne(100.0f * v.z) << 32)
               | ((uint64_t)bf16_rne(100.0f * v.w) << 48);
    *(uint64_t*)&plane[rr * PROW + c4] = p;   // (rr*PROW+c4)*2 is 8B-aligned
  }
  __syncthreads();

  uint32_t cnt = min(cur[b], (uint32_t)cap);
  const v4f* rb = recs + (size_t)b * cap;
  for (uint32_t j = threadIdx.x; j < cnt; j += 1024) {
    v4f rec = __builtin_nontemporal_load(&rb[j]);   // read-once stream
    process_rec(rec, plane, sq, out);
  }

  // exact overflow handling (statistically never: cap = mean + 12 sigma)
  uint32_t nov = min(*ovn, (uint32_t)OVCAP);
  for (uint32_t j = threadIdx.x; j < nov; j += 1024) {
    if (ovbkt[j] == (uint32_t)b) process_rec(ovrec[j], plane, sq, out);
  }
}

// ---------- fallback: direct gather (R1 kernel) ---------------------------
__global__ __launch_bounds__(256) void direct_kernel(
    const float* __restrict__ x, const float* __restrict__ vol,
    float* __restrict__ out, int n)
{
  int i = blockIdx.x * blockDim.x + threadIdx.x;
  if (i >= n) return;
  float gx = x[3 * i + 0] * 2.0f;
  float gy = x[3 * i + 1] * 2.0f;
  float gz = x[3 * i + 2] * 2.0f;
  float ix = ((gx + 1.0f) * 256.0f - 1.0f) * 0.5f;
  float iy = ((gy + 1.0f) * 256.0f - 1.0f) * 0.5f;
  float iz = ((gz + 1.0f) * 256.0f - 1.0f) * 0.5f;
  float x0f = floorf(ix), y0f = floorf(iy), z0f = floorf(iz);
  float tx = ix - x0f, ty = iy - y0f, tz = iz - z0f;
  int x0 = (int)x0f, y0 = (int)y0f, z0 = (int)z0f;
  float wx0 = (x0 >= 0 && x0 < 256) ? (1.0f - tx) : 0.0f;
  float wx1 = (x0 + 1 >= 0 && x0 + 1 < 256) ? tx : 0.0f;
  float wy0 = (y0 >= 0 && y0 < 256) ? (1.0f - ty) : 0.0f;
  float wy1 = (y0 + 1 >= 0 && y0 + 1 < 256) ? ty : 0.0f;
  float wz0 = (z0 >= 0 && z0 < 256) ? (1.0f - tz) : 0.0f;
  float wz1 = (z0 + 1 >= 0 && z0 + 1 < 256) ? tz : 0.0f;
  int xc0 = min(max(x0, 0), 255), xc1 = min(max(x0 + 1, 0), 255);
  int yc0 = min(max(y0, 0), 255), yc1 = min(max(y0 + 1, 0), 255);
  int zc0 = min(max(z0, 0), 255), zc1 = min(max(z0 + 1, 0), 255);
  int r00 = (zc0 * 256 + yc0) * 256;
  int r01 = (zc0 * 256 + yc1) * 256;
  int r10 = (zc1 * 256 + yc0) * 256;
  int r11 = (zc1 * 256 + yc1) * 256;
  float v000 = vol[r00 + xc0], v001 = vol[r00 + xc1];
  float v010 = vol[r01 + xc0], v011 = vol[r01 + xc1];
  float v100 = vol[r10 + xc0], v101 = vol[r10 + xc1];
  float v110 = vol[r11 + xc0], v111 = vol[r11 + xc1];
  float c00 = v000 * wx0 + v001 * wx1;
  float c01 = v010 * wx0 + v011 * wx1;
  float c10 = v100 * wx0 + v101 * wx1;
  float c11 = v110 * wx0 + v111 * wx1;
  float c0 = c00 * wy0 + c01 * wy1;
  float c1 = c10 * wy0 + c11 * wy1;
  out[i] = 100.0f * (c0 * wz0 + c1 * wz1);
}

extern "C" void kernel_launch(void* const* d_in, const int* in_sizes, int n_in,
                              void* d_out, int out_size, void* d_ws, size_t ws_size,
                              hipStream_t stream) {
  const float* x   = (const float*)d_in[0];   // [8, 65536, 3] fp32
  const float* vol = (const float*)d_in[1];   // [256,256,256] fp32
  float* out = (float*)d_out;                 // [8, 65536] fp32
  int n = out_size;                           // 524288

  // workspace layout
  const size_t ovbkt_off = 8192;                   // OVCAP u32 = 262144 B
  const size_t ovrec_off = 270336;                 // OVCAP v4f = 1048576 B
  const size_t recs_off  = 1318912;                // NBUCK * cap * 16
  int cap = (2 * n + NBUCK - 1) / NBUCK;           // mean per bucket (2048)
  cap = cap + cap / 4 + 64;                        // +25% + slack (overflow exact anyway)
  size_t recs_bytes = (size_t)NBUCK * cap * 16;
  size_t need = recs_off + recs_bytes;             // ~22.8 MB

  if (ws_size >= need && n >= 1024) {
    char* ws = (char*)d_ws;
    uint32_t* cur   = (uint32_t*)(ws + 0);         // NBUCK u32
    uint32_t* ovn   = (uint32_t*)(ws + 4096);
    uint32_t* ovbkt = (uint32_t*)(ws + ovbkt_off);
    v4f*      ovrec = (v4f*)(ws + ovrec_off);
    v4f*      recs  = (v4f*)(ws + recs_off);

    (void)hipMemsetAsync(ws, 0, 8192, stream);       // cur + ovn
    (void)hipMemsetAsync(out, 0, (size_t)n * 4, stream);  // atomic accumulators
    scatter_kernel<<<(n + 1023) / 1024, 1024, 0, stream>>>(
        x, cur, ovn, ovbkt, ovrec, recs, cap, n);
    gather_kernel<<<NBUCK, 1024, 0, stream>>>(
        vol, recs, cur, ovn, ovbkt, ovrec, out, cap);
  } else {
    direct_kernel<<<(n + 255) / 256, 256, 0, stream>>>(x, vol, out, n);
  }
}

// Round 6
// 126.420 us; speedup vs baseline: 1.3088x; 1.3088x over previous
//
#include <hip/hip_runtime.h>
#include <stdint.h>

// Trilinear grid_sample of 256^3 fp32 volume, x100. Round 6: z-slab L2
// residency pipeline.
//   scatter: route points into 16 z-slab buckets (16 planes = 4 MB fp32,
//            fits one XCD's L2). Records (ix,iy,iz) written in contiguous
//            per-(block,bucket) runs; inv[i]=slot written coalesced.
//   gather:  slab s pinned to XCD s%8 via blockIdx%8 dispatch round-robin,
//            two temporal phases (slabs 0-7 then 8-15). Warm slab with
//            coalesced reads, then all 8 trilerp taps hit L2. Writes
//            result[slot] coalesced. NO atomics, NO LDS, NO scatter-stores.
//   combine: out[i] = result[inv[i]] -- the only random stream is clean 4B
//            READS over 2.6 MB (cacheable, no dirty-line bouncing).
// R4/R5 lessons baked in: random sub-line DIRTY traffic (NT stores, atomics)
// bounces lines at ~128B/op through the coherence point -- never do it.

#define NSLAB 16
#define OVCAP 16384

typedef float v4f __attribute__((ext_vector_type(4)));

// ---------- scatter: histogram + reservation + record write ---------------
__global__ __launch_bounds__(1024) void scatter_kernel(
    const float* __restrict__ x,
    uint32_t* __restrict__ cur,      // [NSLAB] fill counts (pre-zeroed)
    uint32_t* __restrict__ ovn,      // overflow count (pre-zeroed)
    uint32_t* __restrict__ ovbkt,    // [OVCAP]
    v4f* __restrict__ ovrec,         // [OVCAP] (.w = dest bits)
    v4f* __restrict__ recs,          // [NSLAB * cap]
    uint32_t* __restrict__ inv,      // [n] point -> global slot
    int cap, int n)
{
  __shared__ uint32_t lh[NSLAB];
  __shared__ uint32_t gb[NSLAB];
  int t = threadIdx.x;
  if (t < NSLAB) lh[t] = 0;
  __syncthreads();

  int i = blockIdx.x * 1024 + t;
  bool act = (i < n);
  float ix = 0.f, iy = 0.f, iz = 0.f;
  int b = 0;
  uint32_t lr = 0;
  if (act) {
    float gx = x[3 * i + 0] * 2.0f;
    float gy = x[3 * i + 1] * 2.0f;
    float gz = x[3 * i + 2] * 2.0f;
    ix = ((gx + 1.0f) * 256.0f - 1.0f) * 0.5f;
    iy = ((gy + 1.0f) * 256.0f - 1.0f) * 0.5f;
    iz = ((gz + 1.0f) * 256.0f - 1.0f) * 0.5f;
    int z0 = (int)floorf(iz);                 // [-1, 255]
    b = min(max(z0, 0), 255) >> 4;            // slab of zA
    lr = atomicAdd(&lh[b], 1u);
  }
  __syncthreads();

  if (t < NSLAB) {
    uint32_t c = lh[t];
    gb[t] = c ? atomicAdd(&cur[t], c) : 0u;   // one global atomic per (block,slab)
  }
  __syncthreads();

  if (act) {
    uint32_t p = gb[b] + lr;
    if (p < (uint32_t)cap) {
      uint32_t slot = (uint32_t)b * cap + p;
      v4f r = { ix, iy, iz, 0.0f };
      recs[slot] = r;                         // ~64-rec contiguous runs -> L2
      inv[i] = slot;                          // coalesced
    } else {
      uint32_t o = atomicAdd(ovn, 1u);
      if (o < OVCAP) {
        ovbkt[o] = (uint32_t)b;
        v4f r = { ix, iy, iz, __uint_as_float((uint32_t)i) };
        ovrec[o] = r;
      }
      inv[i] = 0xFFFFFFFFu;                   // combine skips; gather writes out directly
    }
  }
}

// ---------- trilerp from global (L2-resident slab) ------------------------
__device__ __forceinline__ float trilerp_g(
    const float* __restrict__ vol, float ix, float iy, float iz)
{
  float x0f = floorf(ix), y0f = floorf(iy), z0f = floorf(iz);
  float tx = ix - x0f, ty = iy - y0f, tz = iz - z0f;
  int x0 = (int)x0f, y0 = (int)y0f, z0 = (int)z0f;
  float wx0 = (x0 >= 0 && x0 < 256) ? (1.0f - tx) : 0.0f;
  float wx1 = (x0 + 1 >= 0 && x0 + 1 < 256) ? tx : 0.0f;
  float wy0 = (y0 >= 0 && y0 < 256) ? (1.0f - ty) : 0.0f;
  float wy1 = (y0 + 1 >= 0 && y0 + 1 < 256) ? ty : 0.0f;
  float wz0 = (z0 >= 0 && z0 < 256) ? (1.0f - tz) : 0.0f;
  float wz1 = (z0 + 1 >= 0 && z0 + 1 < 256) ? tz : 0.0f;
  int xc0 = min(max(x0, 0), 255), xc1 = min(max(x0 + 1, 0), 255);
  int yc0 = min(max(y0, 0), 255), yc1 = min(max(y0 + 1, 0), 255);
  int zc0 = min(max(z0, 0), 255), zc1 = min(max(z0 + 1, 0), 255);
  int r00 = (zc0 * 256 + yc0) * 256;
  int r01 = (zc0 * 256 + yc1) * 256;
  int r10 = (zc1 * 256 + yc0) * 256;
  int r11 = (zc1 * 256 + yc1) * 256;
  float v000 = vol[r00 + xc0], v001 = vol[r00 + xc1];
  float v010 = vol[r01 + xc0], v011 = vol[r01 + xc1];
  float v100 = vol[r10 + xc0], v101 = vol[r10 + xc1];
  float v110 = vol[r11 + xc0], v111 = vol[r11 + xc1];
  float c00 = v000 * wx0 + v001 * wx1;
  float c01 = v010 * wx0 + v011 * wx1;
  float c10 = v100 * wx0 + v101 * wx1;
  float c11 = v110 * wx0 + v111 * wx1;
  float c0 = c00 * wy0 + c01 * wy1;
  float c1 = c10 * wy0 + c11 * wy1;
  return 100.0f * (c0 * wz0 + c1 * wz1);
}

// ---------- gather: slab-affine blocks, warm L2 then tap it --------------
#define BLK_PER_SLAB 64     // 16 slabs * 64 = 1024 blocks; 512/phase = 2/CU

__global__ __launch_bounds__(512) void gather_kernel(
    const float* __restrict__ vol,
    const v4f* __restrict__ recs,
    const uint32_t* __restrict__ cur,
    const uint32_t* __restrict__ ovn,
    const uint32_t* __restrict__ ovbkt,
    const v4f* __restrict__ ovrec,
    float* __restrict__ result,
    float* __restrict__ out,
    float* __restrict__ sink,
    int cap)
{
  // phase 0: blocks 0..511 -> slabs 0..7; phase 1: 512..1023 -> slabs 8..15.
  // slab % 8 == blockIdx % 8 -> all of a slab's blocks land on one XCD.
  int phase = blockIdx.x >> 9;
  int w = blockIdx.x & 511;
  int s = phase * 8 + (w & 7);
  int jb = w >> 3;                     // 0..63 within slab

  // warm this block's 64 KB chunk of the slab into the XCD-local L2
  const v4f* slab4 = (const v4f*)(vol + (size_t)s * 16 * 256 * 256);
  float acc = 0.0f;
  int base = jb * 4096;                // 4096 v4f = 64 KB
  for (int e = threadIdx.x; e < 4096; e += 512) {
    v4f v = slab4[base + e];
    acc += v.x + v.y + v.z + v.w;
  }
  if (__float_as_uint(acc) == 0xDEADBEEFu) *sink = acc;  // keep loads alive

  // process this slab's records (coalesced reads, coalesced result writes)
  uint32_t cnt = min(cur[s], (uint32_t)cap);
  const v4f* rb = recs + (size_t)s * cap;
  float* resb = result + (size_t)s * cap;
  for (uint32_t j = jb * 512 + threadIdx.x; j < cnt; j += BLK_PER_SLAB * 512) {
    v4f r = __builtin_nontemporal_load(&rb[j]);   // read-once; don't evict slab
    resb[j] = trilerp_g(vol, r.x, r.y, r.z);
  }

  // exact overflow handling (statistically never)
  uint32_t nov = min(*ovn, (uint32_t)OVCAP);
  if (jb == 0) {
    for (uint32_t j = threadIdx.x; j < nov; j += 512) {
      if (ovbkt[j] == (uint32_t)s) {
        v4f r = ovrec[j];
        out[__float_as_uint(r.w)] = trilerp_g(vol, r.x, r.y, r.z);
      }
    }
  }
}

// ---------- combine: permute result back to point order -------------------
__global__ __launch_bounds__(256) void combine_kernel(
    const float* __restrict__ result,
    const uint32_t* __restrict__ inv,
    float* __restrict__ out, int n)
{
  int i = blockIdx.x * 256 + threadIdx.x;
  if (i < n) {
    uint32_t s = inv[i];               // coalesced
    if (s != 0xFFFFFFFFu)
      out[i] = result[s];              // random 4B READ over 2.6 MB (cacheable)
  }
}

// ---------- fallback: direct gather (R1 kernel) ---------------------------
__global__ __launch_bounds__(256) void direct_kernel(
    const float* __restrict__ x, const float* __restrict__ vol,
    float* __restrict__ out, int n)
{
  int i = blockIdx.x * blockDim.x + threadIdx.x;
  if (i >= n) return;
  float gx = x[3 * i + 0] * 2.0f;
  float gy = x[3 * i + 1] * 2.0f;
  float gz = x[3 * i + 2] * 2.0f;
  float ix = ((gx + 1.0f) * 256.0f - 1.0f) * 0.5f;
  float iy = ((gy + 1.0f) * 256.0f - 1.0f) * 0.5f;
  float iz = ((gz + 1.0f) * 256.0f - 1.0f) * 0.5f;
  out[i] = trilerp_g(vol, ix, iy, iz);
}

extern "C" void kernel_launch(void* const* d_in, const int* in_sizes, int n_in,
                              void* d_out, int out_size, void* d_ws, size_t ws_size,
                              hipStream_t stream) {
  const float* x   = (const float*)d_in[0];   // [8, 65536, 3] fp32
  const float* vol = (const float*)d_in[1];   // [256,256,256] fp32
  float* out = (float*)d_out;                 // [8, 65536] fp32
  int n = out_size;                           // 524288

  int m = (n + NSLAB - 1) / NSLAB;            // mean per slab (32768)
  int cap = m + m / 4 + 64;                   // +25% (sigma ~175; overflow exact anyway)

  // workspace layout
  const size_t ovbkt_off = 8192;                       // OVCAP u32 = 64 KB
  const size_t ovrec_off = ovbkt_off + OVCAP * 4;      // OVCAP v4f = 256 KB
  size_t recs_off  = ovrec_off + (size_t)OVCAP * 16;
  size_t recs_b    = (size_t)NSLAB * cap * 16;
  size_t res_off   = recs_off + recs_b;
  size_t res_b     = (size_t)NSLAB * cap * 4;
  size_t inv_off   = res_off + res_b;
  size_t need      = inv_off + (size_t)n * 4;          // ~15.6 MB

  if (ws_size >= need && n == 524288) {
    char* ws = (char*)d_ws;
    uint32_t* cur   = (uint32_t*)(ws + 0);
    uint32_t* ovn   = (uint32_t*)(ws + 4096);
    float*    sink  = (float*)(ws + 6144);
    uint32_t* ovbkt = (uint32_t*)(ws + ovbkt_off);
    v4f*      ovrec = (v4f*)(ws + ovrec_off);
    v4f*      recs  = (v4f*)(ws + recs_off);
    float*    result= (float*)(ws + res_off);
    uint32_t* inv   = (uint32_t*)(ws + inv_off);

    (void)hipMemsetAsync(ws, 0, 8192, stream);       // cur + ovn
    scatter_kernel<<<n / 1024, 1024, 0, stream>>>(
        x, cur, ovn, ovbkt, ovrec, recs, inv, cap, n);
    gather_kernel<<<NSLAB * BLK_PER_SLAB, 512, 0, stream>>>(
        vol, recs, cur, ovn, ovbkt, ovrec, result, out, sink, cap);
    combine_kernel<<<(n + 255) / 256, 256, 0, stream>>>(result, inv, out, n);
  } else {
    direct_kernel<<<(n + 255) / 256, 256, 0, stream>>>(x, vol, out, n);
  }
}